// Round 4
// baseline (278.453 us; speedup 1.0000x reference)
//
#include <hip/hip_runtime.h>

// Causal linear attention (Performer ReLU kernel) via chunked MFMA (bf16).
// B=2 L=4096 H=8 D=64 M=256 fp32 in/out. Chunk T=128, C=32, NBH=16.
// R4: 512-thr blocks, 1 rowtile/wave, Qp kept as reg A-frags (no Aacc spill),
// full-m Kp in LDS -> 1 barrier/kernel, S workspace in bf16, causal tile-skip.
// __launch_bounds__ 2nd arg == min BLOCKS/CU on this stack (R2/R3 evidence):
// (512,1) -> 8 waves/CU -> 256-VGPR cap, no spill.
// ws: S bf16 [NBH][C][D][M] (16.8 MB) then Z fp32 [NBH][C][M] (0.5 MB).

#define B_   2
#define L_   4096
#define H_   8
#define D_   64
#define M_   256
#define T_   128
#define C_   (L_ / T_)   // 32
#define NBH  (B_ * H_)   // 16
#define RATIO 0.0625f    // 1/sqrt(256)
#define STAB  0.001f
#define SVT  136         // VT/Am/KpT row stride (272B: 16B-aligned, 2-way banks)
#define SKP  264         // KpL row stride (528B: 16B-aligned, 2-way banks)
#define SQS  72          // QpStage row stride

typedef __attribute__((ext_vector_type(8))) short short8;
typedef __attribute__((ext_vector_type(4))) float floatx4;

#define MFMA16(a, b, c) __builtin_amdgcn_mfma_f32_16x16x32_bf16(a, b, c, 0, 0, 0)

__device__ inline unsigned short f2bf(float x) {
    union { float f; unsigned u; } v; v.f = x;
    unsigned r = v.u + 0x7FFF + ((v.u >> 16) & 1);
    return (unsigned short)(r >> 16);
}
__device__ inline float bf2f(unsigned short b) {
    union { unsigned u; float f; } v; v.u = ((unsigned)b) << 16; return v.f;
}
__device__ inline short8 ldg8_bf(const float* p) {
    float4 a = *(const float4*)p;
    float4 b = *(const float4*)(p + 4);
    short8 r;
    r[0] = (short)f2bf(a.x); r[1] = (short)f2bf(a.y);
    r[2] = (short)f2bf(a.z); r[3] = (short)f2bf(a.w);
    r[4] = (short)f2bf(b.x); r[5] = (short)f2bf(b.y);
    r[6] = (short)f2bf(b.z); r[7] = (short)f2bf(b.w);
    return r;
}

// ---------------- Phase 1: Kp, S_c = V^T.Kp (bf16), z_c ----------------
// 512 thr / 8 waves. Wave w owns K rows 16w..16w+15. One barrier.
__global__ __launch_bounds__(512, 1)
void phase1_kernel(const float* __restrict__ key, const float* __restrict__ val,
                   const float* __restrict__ proj,
                   unsigned short* __restrict__ S, float* __restrict__ Z) {
    const int c = blockIdx.x, bh = blockIdx.y;
    const int b = bh / H_, h = bh % H_;
    const int tid = threadIdx.x;
    const int w = tid >> 6, lane = tid & 63;
    const int l15 = lane & 15, quad = lane >> 4;

    __shared__ __align__(16) unsigned short VT[64 * SVT];    // V^T [d][t]
    __shared__ __align__(16) unsigned short KpT[M_ * SVT];   // Kp^T [m][t]
    __shared__ float zP[8][M_];

    const size_t rowstr = H_ * D_;
    const size_t base = ((size_t)b * L_ + (size_t)c * T_) * rowstr + (size_t)h * D_;

    for (int i = tid; i < T_ * 16; i += 512) {
        int t = i >> 4, d4 = (i & 15) * 4;
        float4 vv = *(const float4*)(val + base + (size_t)t * rowstr + d4);
        VT[(d4 + 0) * SVT + t] = f2bf(vv.x);
        VT[(d4 + 1) * SVT + t] = f2bf(vv.y);
        VT[(d4 + 2) * SVT + t] = f2bf(vv.z);
        VT[(d4 + 3) * SVT + t] = f2bf(vv.w);
    }
    short8 kf[2];
#pragma unroll
    for (int kk = 0; kk < 2; ++kk)
        kf[kk] = ldg8_bf(key + base + (size_t)(16 * w + l15) * rowstr + kk * 32 + quad * 8);

    for (int fg = 0; fg < 4; ++fg) {
        short8 pf[4][2];
#pragma unroll
        for (int ct = 0; ct < 4; ++ct)
#pragma unroll
            for (int kk = 0; kk < 2; ++kk)
                pf[ct][kk] = ldg8_bf(proj + (size_t)(fg * 64 + ct * 16 + l15) * D_
                                     + kk * 32 + quad * 8);
#pragma unroll
        for (int ct = 0; ct < 4; ++ct) {
            floatx4 a = {0.f, 0.f, 0.f, 0.f};
            a = MFMA16(kf[0], pf[ct][0], a);
            a = MFMA16(kf[1], pf[ct][1], a);
            float zrow = 0.f;
            const int m = fg * 64 + ct * 16 + l15;
#pragma unroll
            for (int r = 0; r < 4; ++r) {
                float kpf = fmaxf(RATIO * a[r], 0.f) + STAB;
                KpT[m * SVT + 16 * w + quad * 4 + r] = f2bf(kpf);
                zrow += kpf;
            }
            zrow += __shfl_xor(zrow, 16, 64);
            zrow += __shfl_xor(zrow, 32, 64);
            if (quad == 0) zP[w][m] = zrow;     // full 16-row tile sum
        }
    }
    __syncthreads();   // the only barrier: VT, KpT, zP visible

    // S[d][m] = V^T . Kp  — wave w: d-tile (w&3), m-half (w>>2)
    const int dtile = w & 3, mh = w >> 2;
    short8 vf[4];
#pragma unroll
    for (int k4 = 0; k4 < 4; ++k4)
        vf[k4] = *(const short8*)&VT[(16 * dtile + l15) * SVT + k4 * 32 + quad * 8];
    unsigned short* Sp = S + (size_t)(bh * C_ + c) * (M_ * D_);
#pragma unroll
    for (int ct2 = 0; ct2 < 8; ++ct2) {
        floatx4 acc = {0.f, 0.f, 0.f, 0.f};
#pragma unroll
        for (int k4 = 0; k4 < 4; ++k4) {
            short8 kb = *(const short8*)&KpT[(mh * 128 + ct2 * 16 + l15) * SVT
                                             + k4 * 32 + quad * 8];
            acc = MFMA16(vf[k4], kb, acc);
        }
#pragma unroll
        for (int r = 0; r < 4; ++r)
            Sp[(size_t)(16 * dtile + quad * 4 + r) * M_
               + mh * 128 + ct2 * 16 + l15] = f2bf(acc[r]);
    }
    if (tid < M_) {
        float z = 0.f;
#pragma unroll
        for (int ww = 0; ww < 8; ++ww) z += zP[ww][tid];
        Z[(size_t)(bh * C_ + c) * M_ + tid] = z;
    }
}

// ---------------- Phase 2: exclusive prefix over chunks (in place) --------
__global__ void phase2_kernel(unsigned int* __restrict__ S2, float* __restrict__ Z) {
    const int bh = blockIdx.y;
    const int j = blockIdx.x * 256 + threadIdx.x;
    const int NP = M_ * D_ / 2;   // 8192 bf16-pairs per chunk
    if (j < NP) {
        unsigned int* p = S2 + (size_t)bh * C_ * NP + j;
        float r0 = 0.f, r1 = 0.f;
        for (int c = 0; c < C_; ++c) {
            unsigned int v = p[(size_t)c * NP];
            p[(size_t)c * NP] = (unsigned int)f2bf(r0) | ((unsigned int)f2bf(r1) << 16);
            r0 += bf2f((unsigned short)(v & 0xffff));
            r1 += bf2f((unsigned short)(v >> 16));
        }
    } else {
        const int j2 = j - NP;
        if (j2 < M_) {
            float run = 0.f;
            float* pz = Z + (size_t)bh * C_ * M_ + j2;
            for (int c = 0; c < C_; ++c) {
                float t = pz[c * M_];
                pz[c * M_] = run;
                run += t;
            }
        }
    }
}

// ---------------- Phase 3: per-chunk output via MFMA ----------
// 512 thr / 8 waves; wave w owns output rows 16w..16w+15. One barrier.
__global__ __launch_bounds__(512, 1)
void phase3_kernel(const float* __restrict__ q, const float* __restrict__ key,
                   const float* __restrict__ val, const float* __restrict__ proj,
                   const unsigned short* __restrict__ S, const float* __restrict__ Z,
                   float* __restrict__ out) {
    const int c = blockIdx.x, bh = blockIdx.y;
    const int b = bh / H_, h = bh % H_;
    const int tid = threadIdx.x;
    const int w = tid >> 6, lane = tid & 63;
    const int l15 = lane & 15, quad = lane >> 4;

    __shared__ __align__(16) unsigned short KpL[T_ * SKP];   // Kp [t][m] full-m
    __shared__ __align__(16) unsigned short VT[64 * SVT];    // V^T [d][t]
    __shared__ __align__(16) unsigned short AmL[T_ * SVT];   // masked A [t][tc]
    __shared__ __align__(16) unsigned short QpS[8 * 16 * SQS]; // per-wave stage

    const size_t rowstr = H_ * D_;
    const size_t base = ((size_t)b * L_ + (size_t)c * T_) * rowstr + (size_t)h * D_;
    const unsigned short* Sp = S + (size_t)(bh * C_ + c) * (M_ * D_);
    const float* Zp = Z + (size_t)(bh * C_ + c) * M_;

    for (int i = tid; i < T_ * 16; i += 512) {
        int t = i >> 4, d4 = (i & 15) * 4;
        float4 vv = *(const float4*)(val + base + (size_t)t * rowstr + d4);
        VT[(d4 + 0) * SVT + t] = f2bf(vv.x);
        VT[(d4 + 1) * SVT + t] = f2bf(vv.y);
        VT[(d4 + 2) * SVT + t] = f2bf(vv.z);
        VT[(d4 + 3) * SVT + t] = f2bf(vv.w);
    }
    short8 qf[2], kf[2];
#pragma unroll
    for (int kk = 0; kk < 2; ++kk) {
        size_t ro = base + (size_t)(16 * w + l15) * rowstr + kk * 32 + quad * 8;
        qf[kk] = ldg8_bf(q + ro);
        kf[kk] = ldg8_bf(key + ro);
    }

    unsigned short* myQp = QpS + w * 16 * SQS;
    short8 qa[8];              // Qp A-frags, own 16 rows x all 256 m (bf16)
    float dz[4] = {0.f, 0.f, 0.f, 0.f};

    for (int fg = 0; fg < 4; ++fg) {
        short8 pf[4][2];
#pragma unroll
        for (int ct = 0; ct < 4; ++ct)
#pragma unroll
            for (int kk = 0; kk < 2; ++kk)
                pf[ct][kk] = ldg8_bf(proj + (size_t)(fg * 64 + ct * 16 + l15) * D_
                                     + kk * 32 + quad * 8);
#pragma unroll
        for (int ct = 0; ct < 4; ++ct) {
            floatx4 aq = {0.f, 0.f, 0.f, 0.f};
            aq = MFMA16(qf[0], pf[ct][0], aq);
            aq = MFMA16(qf[1], pf[ct][1], aq);
            floatx4 ak = {0.f, 0.f, 0.f, 0.f};
            ak = MFMA16(kf[0], pf[ct][0], ak);
            ak = MFMA16(kf[1], pf[ct][1], ak);
            const int mcol = fg * 64 + ct * 16 + l15;
            float zv = Zp[mcol];
#pragma unroll
            for (int r = 0; r < 4; ++r) {
                float qpv = fmaxf(RATIO * aq[r], 0.f) + STAB;
                float kpv = fmaxf(RATIO * ak[r], 0.f) + STAB;
                myQp[(quad * 4 + r) * SQS + ct * 16 + l15] = f2bf(qpv);
                KpL[(size_t)(16 * w + quad * 4 + r) * SKP + mcol] = f2bf(kpv);
                dz[r] = fmaf(qpv, zv, dz[r]);
            }
        }
        // read back own-wave A-frags (same-wave LDS dep; no barrier)
#pragma unroll
        for (int kk = 0; kk < 2; ++kk)
            qa[fg * 2 + kk] = *(const short8*)&myQp[l15 * SQS + kk * 32 + quad * 8];
    }
#pragma unroll
    for (int r = 0; r < 4; ++r) {
        dz[r] += __shfl_xor(dz[r], 1, 64);
        dz[r] += __shfl_xor(dz[r], 2, 64);
        dz[r] += __shfl_xor(dz[r], 4, 64);
        dz[r] += __shfl_xor(dz[r], 8, 64);
    }

    // num = Qp . S_prefix   (S bf16 [d][m], direct short8 global loads)
    floatx4 num[4];
#pragma unroll
    for (int dt = 0; dt < 4; ++dt) {
        floatx4 z4 = {0.f, 0.f, 0.f, 0.f};
        num[dt] = z4;
    }
#pragma unroll
    for (int dt = 0; dt < 4; ++dt)
#pragma unroll
        for (int kc = 0; kc < 8; ++kc) {
            short8 sb = *(const short8*)(Sp + (size_t)(dt * 16 + l15) * M_
                                         + kc * 32 + quad * 8);
            num[dt] = MFMA16(qa[kc], sb, num[dt]);
        }

    __syncthreads();   // the only barrier: KpL + VT visible

    // A = Qp.Kp^T, causal tile-skip (wave-uniform: tiles ct>w fully masked)
    floatx4 Aacc[8];
#pragma unroll
    for (int ct = 0; ct < 8; ++ct) {
        floatx4 acc = {0.f, 0.f, 0.f, 0.f};
        if (ct <= w) {
#pragma unroll
            for (int kc = 0; kc < 8; ++kc) {
                short8 kb = *(const short8*)&KpL[(size_t)(ct * 16 + l15) * SKP
                                                 + kc * 32 + quad * 8];
                acc = MFMA16(qa[kc], kb, acc);
            }
        }
        Aacc[ct] = acc;
    }
    // mask (exact on diagonal tile), row-sum denA, write Am (own rows)
    float da[4] = {0.f, 0.f, 0.f, 0.f};
#pragma unroll
    for (int ct = 0; ct < 8; ++ct)
#pragma unroll
        for (int r = 0; r < 4; ++r) {
            float av = Aacc[ct][r];
            if (ct > w || (ct == w && l15 > quad * 4 + r)) av = 0.f;
            AmL[(size_t)(16 * w + quad * 4 + r) * SVT + ct * 16 + l15] = f2bf(av);
            da[r] += av;
        }
#pragma unroll
    for (int r = 0; r < 4; ++r) {
        da[r] += __shfl_xor(da[r], 1, 64);
        da[r] += __shfl_xor(da[r], 2, 64);
        da[r] += __shfl_xor(da[r], 4, 64);
        da[r] += __shfl_xor(da[r], 8, 64);
    }

    // num += A_masked . V  (own rows; k4 tiles beyond diagonal are all-zero)
    for (int k4 = 0; k4 <= (w >> 1); ++k4) {
        short8 am = *(const short8*)&AmL[(size_t)(16 * w + l15) * SVT
                                         + k4 * 32 + quad * 8];
#pragma unroll
        for (int dt = 0; dt < 4; ++dt) {
            short8 vb = *(const short8*)&VT[(dt * 16 + l15) * SVT + k4 * 32 + quad * 8];
            num[dt] = MFMA16(am, vb, num[dt]);
        }
    }

    // epilogue
#pragma unroll
    for (int r = 0; r < 4; ++r) {
        float den = da[r] + dz[r];
        if (den <= 0.f) den = 1.f;
        float inv = 1.f / den;
        int t = 16 * w + quad * 4 + r;
#pragma unroll
        for (int dt = 0; dt < 4; ++dt)
            out[base + (size_t)t * rowstr + dt * 16 + l15] = num[dt][r] * inv;
    }
}

extern "C" void kernel_launch(void* const* d_in, const int* in_sizes, int n_in,
                              void* d_out, int out_size, void* d_ws, size_t ws_size,
                              hipStream_t stream) {
    const float* q    = (const float*)d_in[0];
    const float* k    = (const float*)d_in[1];
    const float* v    = (const float*)d_in[2];
    const float* proj = (const float*)d_in[3];
    float* out = (float*)d_out;

    unsigned short* S = (unsigned short*)d_ws;                 // bf16 S
    float* Z = (float*)(S + (size_t)NBH * C_ * M_ * D_);       // fp32 Z

    dim3 g1(C_, NBH);
    phase1_kernel<<<g1, dim3(512), 0, stream>>>(k, v, proj, S, Z);
    dim3 g2(33, NBH);   // 8192 S-pairs + 256 Z per bh
    phase2_kernel<<<g2, dim3(256), 0, stream>>>((unsigned int*)S, Z);
    phase3_kernel<<<g1, dim3(512), 0, stream>>>(q, k, v, proj, S, Z, out);
}

// Round 5
// 188.722 us; speedup vs baseline: 1.4755x; 1.4755x over previous
//
#include <hip/hip_runtime.h>

// Causal linear attention (Performer ReLU kernel) via chunked MFMA (bf16).
// B=2 L=4096 H=8 D=64 M=256 fp32 in/out. Chunk T=128, C=32, NBH=16.
// R5: m-halved LDS tiles so phase1/phase3 fit 2 blocks/CU (R4 post-mortem:
// 138 KB LDS -> 1 block/CU -> 2 sequential rounds -> 2x dur). Qp A-frags in
// regs per half; Am overlays KpL; 4 barriers/kernel.
// __launch_bounds__ 2nd arg == min BLOCKS/CU on this stack (R2/R3 evidence).
// ws: S bf16 [NBH][C][D][M] (16.8 MB) then Z fp32 [NBH][C][M] (0.5 MB).

#define B_   2
#define L_   4096
#define H_   8
#define D_   64
#define M_   256
#define T_   128
#define C_   (L_ / T_)   // 32
#define NBH  (B_ * H_)   // 16
#define RATIO 0.0625f    // 1/sqrt(256)
#define STAB  0.001f
#define SVT  136         // VT / KpT / KpL / Am row stride (272B, 16B-aligned)
#define SQS  72          // Qp stage row stride

typedef __attribute__((ext_vector_type(8))) short short8;
typedef __attribute__((ext_vector_type(4))) float floatx4;

#define MFMA16(a, b, c) __builtin_amdgcn_mfma_f32_16x16x32_bf16(a, b, c, 0, 0, 0)

__device__ inline unsigned short f2bf(float x) {
    union { float f; unsigned u; } v; v.f = x;
    unsigned r = v.u + 0x7FFF + ((v.u >> 16) & 1);
    return (unsigned short)(r >> 16);
}
__device__ inline float bf2f(unsigned short b) {
    union { unsigned u; float f; } v; v.u = ((unsigned)b) << 16; return v.f;
}
__device__ inline short8 ldg8_bf(const float* p) {
    float4 a = *(const float4*)p;
    float4 b = *(const float4*)(p + 4);
    short8 r;
    r[0] = (short)f2bf(a.x); r[1] = (short)f2bf(a.y);
    r[2] = (short)f2bf(a.z); r[3] = (short)f2bf(a.w);
    r[4] = (short)f2bf(b.x); r[5] = (short)f2bf(b.y);
    r[6] = (short)f2bf(b.z); r[7] = (short)f2bf(b.w);
    return r;
}

// ---------------- Phase 1: Kp, S_c = V^T.Kp (bf16), z_c ----------------
// 512 thr / 8 waves. Wave w owns Kp rows 16w..16w+15. m processed in two
// 128-halves (KpT [mloc][t]); S waves = (dtile = w&3, mq = w>>2).
__global__ __launch_bounds__(512, 2)
void phase1_kernel(const float* __restrict__ key, const float* __restrict__ val,
                   const float* __restrict__ proj,
                   unsigned short* __restrict__ S, float* __restrict__ Z) {
    const int c = blockIdx.x, bh = blockIdx.y;
    const int b = bh / H_, h = bh % H_;
    const int tid = threadIdx.x;
    const int w = tid >> 6, lane = tid & 63;
    const int l15 = lane & 15, quad = lane >> 4;

    __shared__ __align__(16) unsigned short VT[64 * SVT];     // V^T [d][t]
    __shared__ __align__(16) unsigned short KpT[128 * SVT];   // Kp^T [mloc][t]
    __shared__ float zP[8][M_];

    const size_t rowstr = H_ * D_;
    const size_t base = ((size_t)b * L_ + (size_t)c * T_) * rowstr + (size_t)h * D_;

    for (int i = tid; i < T_ * 16; i += 512) {
        int t = i >> 4, d4 = (i & 15) * 4;
        float4 vv = *(const float4*)(val + base + (size_t)t * rowstr + d4);
        VT[(d4 + 0) * SVT + t] = f2bf(vv.x);
        VT[(d4 + 1) * SVT + t] = f2bf(vv.y);
        VT[(d4 + 2) * SVT + t] = f2bf(vv.z);
        VT[(d4 + 3) * SVT + t] = f2bf(vv.w);
    }
    short8 kf[2];
#pragma unroll
    for (int kk = 0; kk < 2; ++kk)
        kf[kk] = ldg8_bf(key + base + (size_t)(16 * w + l15) * rowstr + kk * 32 + quad * 8);

    const int dtile = w & 3, mq = w >> 2;
    short8 vf[4];
    unsigned short* Sp = S + (size_t)(bh * C_ + c) * (M_ * D_);

    for (int hh = 0; hh < 2; ++hh) {
#pragma unroll
        for (int fgl = 0; fgl < 2; ++fgl) {
            const int fg = 2 * hh + fgl;
#pragma unroll
            for (int ct = 0; ct < 4; ++ct) {
                short8 pf0 = ldg8_bf(proj + (size_t)(fg * 64 + ct * 16 + l15) * D_ + quad * 8);
                short8 pf1 = ldg8_bf(proj + (size_t)(fg * 64 + ct * 16 + l15) * D_ + 32 + quad * 8);
                floatx4 a = {0.f, 0.f, 0.f, 0.f};
                a = MFMA16(kf[0], pf0, a);
                a = MFMA16(kf[1], pf1, a);
                const int mloc = fgl * 64 + ct * 16 + l15;
                float zrow = 0.f;
#pragma unroll
                for (int r = 0; r < 4; ++r) {
                    float kpf = fmaxf(RATIO * a[r], 0.f) + STAB;
                    KpT[mloc * SVT + 16 * w + quad * 4 + r] = f2bf(kpf);
                    zrow += kpf;
                }
                zrow += __shfl_xor(zrow, 16, 64);
                zrow += __shfl_xor(zrow, 32, 64);
                if (quad == 0) zP[w][hh * 128 + mloc] = zrow;
            }
        }
        __syncthreads();   // KpT half (+ VT on hh=0) ready
        if (hh == 0) {
#pragma unroll
            for (int k4 = 0; k4 < 4; ++k4)
                vf[k4] = *(const short8*)&VT[(16 * dtile + l15) * SVT + k4 * 32 + quad * 8];
        }
#pragma unroll
        for (int ct2 = 0; ct2 < 4; ++ct2) {
            const int mrow = mq * 64 + ct2 * 16 + l15;
            floatx4 acc = {0.f, 0.f, 0.f, 0.f};
#pragma unroll
            for (int k4 = 0; k4 < 4; ++k4) {
                short8 kb = *(const short8*)&KpT[mrow * SVT + k4 * 32 + quad * 8];
                acc = MFMA16(vf[k4], kb, acc);
            }
#pragma unroll
            for (int r = 0; r < 4; ++r)
                Sp[(size_t)(16 * dtile + quad * 4 + r) * M_
                   + hh * 128 + mq * 64 + ct2 * 16 + l15] = f2bf(acc[r]);
        }
        __syncthreads();   // S-half reads done (next half overwrites KpT)
    }
    if (tid < M_) {
        float z = 0.f;
#pragma unroll
        for (int ww = 0; ww < 8; ++ww) z += zP[ww][tid];
        Z[(size_t)(bh * C_ + c) * M_ + tid] = z;
    }
}

// ---------------- Phase 2: exclusive prefix over chunks (in place) --------
__global__ void phase2_kernel(unsigned int* __restrict__ S2, float* __restrict__ Z) {
    const int bh = blockIdx.y;
    const int j = blockIdx.x * 256 + threadIdx.x;
    const int NP = M_ * D_ / 2;   // 8192 bf16-pairs per chunk
    if (j < NP) {
        unsigned int* p = S2 + (size_t)bh * C_ * NP + j;
        float r0 = 0.f, r1 = 0.f;
        for (int c = 0; c < C_; ++c) {
            unsigned int v = p[(size_t)c * NP];
            p[(size_t)c * NP] = (unsigned int)f2bf(r0) | ((unsigned int)f2bf(r1) << 16);
            r0 += bf2f((unsigned short)(v & 0xffff));
            r1 += bf2f((unsigned short)(v >> 16));
        }
    } else {
        const int j2 = j - NP;
        if (j2 < M_) {
            float run = 0.f;
            float* pz = Z + (size_t)bh * C_ * M_ + j2;
            for (int c = 0; c < C_; ++c) {
                float t = pz[c * M_];
                pz[c * M_] = run;
                run += t;
            }
        }
    }
}

// ---------------- Phase 3: per-chunk output via MFMA ----------
// 512 thr / 8 waves; wave w owns output rows 16w..16w+15. m in two halves:
// fg{0,1} -> KpL half -> A += Qp.Kp^T, barrier, fg{2,3} -> second half.
// Am overlays KpL after the final A barrier (wave-private rows).
__global__ __launch_bounds__(512, 2)
void phase3_kernel(const float* __restrict__ q, const float* __restrict__ key,
                   const float* __restrict__ val, const float* __restrict__ proj,
                   const unsigned short* __restrict__ S, const float* __restrict__ Z,
                   float* __restrict__ out) {
    const int c = blockIdx.x, bh = blockIdx.y;
    const int b = bh / H_, h = bh % H_;
    const int tid = threadIdx.x;
    const int w = tid >> 6, lane = tid & 63;
    const int l15 = lane & 15, quad = lane >> 4;

    __shared__ __align__(16) unsigned short KpL[T_ * SVT];     // [t][mloc]; Am overlays
    __shared__ __align__(16) unsigned short VT[64 * SVT];      // V^T [d][t]
    __shared__ __align__(16) unsigned short QpS[8 * 16 * SQS]; // per-wave stage

    const size_t rowstr = H_ * D_;
    const size_t base = ((size_t)b * L_ + (size_t)c * T_) * rowstr + (size_t)h * D_;
    const unsigned short* Sp = S + (size_t)(bh * C_ + c) * (M_ * D_);
    const float* Zp = Z + (size_t)(bh * C_ + c) * M_;

    for (int i = tid; i < T_ * 16; i += 512) {
        int t = i >> 4, d4 = (i & 15) * 4;
        float4 vv = *(const float4*)(val + base + (size_t)t * rowstr + d4);
        VT[(d4 + 0) * SVT + t] = f2bf(vv.x);
        VT[(d4 + 1) * SVT + t] = f2bf(vv.y);
        VT[(d4 + 2) * SVT + t] = f2bf(vv.z);
        VT[(d4 + 3) * SVT + t] = f2bf(vv.w);
    }
    short8 qf[2], kf[2];
#pragma unroll
    for (int kk = 0; kk < 2; ++kk) {
        size_t ro = base + (size_t)(16 * w + l15) * rowstr + kk * 32 + quad * 8;
        qf[kk] = ldg8_bf(q + ro);
        kf[kk] = ldg8_bf(key + ro);
    }

    unsigned short* myQp = QpS + w * 16 * SQS;
    floatx4 num[4];
    floatx4 Aacc[8];
#pragma unroll
    for (int dt = 0; dt < 4; ++dt) { floatx4 z4 = {0.f,0.f,0.f,0.f}; num[dt] = z4; }
#pragma unroll
    for (int ct = 0; ct < 8; ++ct) { floatx4 z4 = {0.f,0.f,0.f,0.f}; Aacc[ct] = z4; }
    float dz[4] = {0.f, 0.f, 0.f, 0.f};

    for (int hh = 0; hh < 2; ++hh) {
        short8 qa[4];
#pragma unroll
        for (int fgl = 0; fgl < 2; ++fgl) {
            const int fg = 2 * hh + fgl;
#pragma unroll
            for (int ct = 0; ct < 4; ++ct) {
                const float* pp = proj + (size_t)(fg * 64 + ct * 16 + l15) * D_;
                short8 pf0 = ldg8_bf(pp + quad * 8);
                short8 pf1 = ldg8_bf(pp + 32 + quad * 8);
                floatx4 aq = {0.f, 0.f, 0.f, 0.f};
                aq = MFMA16(qf[0], pf0, aq);
                aq = MFMA16(qf[1], pf1, aq);
                floatx4 ak = {0.f, 0.f, 0.f, 0.f};
                ak = MFMA16(kf[0], pf0, ak);
                ak = MFMA16(kf[1], pf1, ak);
                const int mloc = fgl * 64 + ct * 16 + l15;
                float zv = Zp[hh * 128 + mloc];
#pragma unroll
                for (int r = 0; r < 4; ++r) {
                    float qpv = fmaxf(RATIO * aq[r], 0.f) + STAB;
                    float kpv = fmaxf(RATIO * ak[r], 0.f) + STAB;
                    myQp[(quad * 4 + r) * SQS + ct * 16 + l15] = f2bf(qpv);
                    KpL[(size_t)(16 * w + quad * 4 + r) * SVT + mloc] = f2bf(kpv);
                    dz[r] = fmaf(qpv, zv, dz[r]);
                }
            }
            // read back own-wave A-frags (same-wave LDS dep; no barrier)
#pragma unroll
            for (int kk = 0; kk < 2; ++kk)
                qa[fgl * 2 + kk] = *(const short8*)&myQp[l15 * SQS + kk * 32 + quad * 8];
        }
        // num += Qp . S_prefix (this m-half; bf16 global B-frags)
#pragma unroll
        for (int dt = 0; dt < 4; ++dt)
#pragma unroll
            for (int kc = 0; kc < 4; ++kc) {
                short8 sb = *(const short8*)(Sp + (size_t)(dt * 16 + l15) * M_
                                             + hh * 128 + kc * 32 + quad * 8);
                num[dt] = MFMA16(qa[kc], sb, num[dt]);
            }
        __syncthreads();   // KpL half complete
        // A += Qp.Kp^T over this half; causal tile-skip (wave-uniform)
#pragma unroll
        for (int ct = 0; ct < 8; ++ct) {
            if (ct <= w) {
#pragma unroll
                for (int kc = 0; kc < 4; ++kc) {
                    short8 kb = *(const short8*)&KpL[(size_t)(ct * 16 + l15) * SVT
                                                     + kc * 32 + quad * 8];
                    Aacc[ct] = MFMA16(qa[kc], kb, Aacc[ct]);
                }
            }
        }
        __syncthreads();   // A reads done (next half / Am overlay may write)
    }
#pragma unroll
    for (int r = 0; r < 4; ++r) {
        dz[r] += __shfl_xor(dz[r], 1, 64);
        dz[r] += __shfl_xor(dz[r], 2, 64);
        dz[r] += __shfl_xor(dz[r], 4, 64);
        dz[r] += __shfl_xor(dz[r], 8, 64);
    }

    // mask (exact on diagonal tile), row-sum denA, write Am (own rows, KpL overlay)
    unsigned short* AmL = KpL;
    float da[4] = {0.f, 0.f, 0.f, 0.f};
#pragma unroll
    for (int ct = 0; ct < 8; ++ct)
#pragma unroll
        for (int r = 0; r < 4; ++r) {
            float av = Aacc[ct][r];
            if (ct > w || (ct == w && l15 > quad * 4 + r)) av = 0.f;
            AmL[(size_t)(16 * w + quad * 4 + r) * SVT + ct * 16 + l15] = f2bf(av);
            da[r] += av;
        }
#pragma unroll
    for (int r = 0; r < 4; ++r) {
        da[r] += __shfl_xor(da[r], 1, 64);
        da[r] += __shfl_xor(da[r], 2, 64);
        da[r] += __shfl_xor(da[r], 4, 64);
        da[r] += __shfl_xor(da[r], 8, 64);
    }

    // num += A_masked . V  (own rows; k4 tiles beyond diagonal are all-zero)
    for (int k4 = 0; k4 <= (w >> 1); ++k4) {
        short8 am = *(const short8*)&AmL[(size_t)(16 * w + l15) * SVT
                                         + k4 * 32 + quad * 8];
#pragma unroll
        for (int dt = 0; dt < 4; ++dt) {
            short8 vb = *(const short8*)&VT[(dt * 16 + l15) * SVT + k4 * 32 + quad * 8];
            num[dt] = MFMA16(am, vb, num[dt]);
        }
    }

    // epilogue
#pragma unroll
    for (int r = 0; r < 4; ++r) {
        float den = da[r] + dz[r];
        if (den <= 0.f) den = 1.f;
        float inv = 1.f / den;
        int t = 16 * w + quad * 4 + r;
#pragma unroll
        for (int dt = 0; dt < 4; ++dt)
            out[base + (size_t)t * rowstr + dt * 16 + l15] = num[dt][r] * inv;
    }
}

extern "C" void kernel_launch(void* const* d_in, const int* in_sizes, int n_in,
                              void* d_out, int out_size, void* d_ws, size_t ws_size,
                              hipStream_t stream) {
    const float* q    = (const float*)d_in[0];
    const float* k    = (const float*)d_in[1];
    const float* v    = (const float*)d_in[2];
    const float* proj = (const float*)d_in[3];
    float* out = (float*)d_out;

    unsigned short* S = (unsigned short*)d_ws;                 // bf16 S
    float* Z = (float*)(S + (size_t)NBH * C_ * M_ * D_);       // fp32 Z

    dim3 g1(C_, NBH);
    phase1_kernel<<<g1, dim3(512), 0, stream>>>(k, v, proj, S, Z);
    dim3 g2(33, NBH);   // 8192 S-pairs + 256 Z per bh
    phase2_kernel<<<g2, dim3(256), 0, stream>>>((unsigned int*)S, Z);
    phase3_kernel<<<g1, dim3(512), 0, stream>>>(q, k, v, proj, S, Z, out);
}